// Round 4
// baseline (8393.256 us; speedup 1.0000x reference)
//
#include <hip/hip_runtime.h>
#include <math.h>

#define Bn 128
#define Tn 64
#define Cn 64
#define Wn 27
#define Hn 128
#define EPSf 1e-5f
#define NBWf 3456.0f

struct Params {
  const float* in;
  const float4* wt_g0; const float* gb0;
  const float4* wt_c0; const float* cb0;
  const float4* wt_a0; const float* ab0;
  const float* bg0; const float* bb0;
  const float4* wt_g1; const float* gb1;
  const float4* wt_c1; const float* cb1;
  const float4* wt_a1; const float* ab1;
  const float* bg1; const float* bb1;
  const float* concw;
  float* pre1a; float* pre1b; float* pre2a; float* pre2b;
  float* sums;        // [2*64][256] : per (layer,t) 128 ch x (sum, sumsq)
  unsigned* cnt;      // global barrier counter
  float* out;
};

__device__ __forceinline__ void bn_coef(const float* __restrict__ sums,
                                        const float* __restrict__ g,
                                        const float* __restrict__ b,
                                        int c, float& sc, float& sh) {
  float s1 = sums[2 * c], s2 = sums[2 * c + 1];
  float mean = s1 * (1.0f / NBWf);
  float var = s2 * (1.0f / NBWf) - mean * mean;
  sc = g[c] * rsqrtf(var + EPSf);
  sh = b[c] - mean * sc;
}

__device__ __forceinline__ float sigm(float x) {
  return 1.0f / (1.0f + __expf(-x));
}

// swizzled scalar index: row stride 32 floats; 16B blocks XORed by (row&7)
__device__ __forceinline__ int swz(int row, int c) {
  return row * 32 + ((((c >> 2) ^ (row & 7)) & 7) << 2) + (c & 3);
}

// one conv row: acc[27] += w0*x[c-1] + w1*x[c] + w2*x[c+1], cols 0..28
// (col 0 and 28 are zero pads), x read as swizzled float4 blocks.
__device__ __forceinline__ void conv_row(const float* __restrict__ rowbase,
                                         int sw, float w0, float w1, float w2,
                                         float* __restrict__ acc) {
  const float4* rp = (const float4*)rowbase;
  float xa[16];
  {
    float4 v0 = rp[0 ^ sw];
    float4 v1 = rp[1 ^ sw];
    float4 v2 = rp[2 ^ sw];
    float4 v3 = rp[3 ^ sw];
    xa[0] = v0.x; xa[1] = v0.y; xa[2] = v0.z; xa[3] = v0.w;
    xa[4] = v1.x; xa[5] = v1.y; xa[6] = v1.z; xa[7] = v1.w;
    xa[8] = v2.x; xa[9] = v2.y; xa[10] = v2.z; xa[11] = v2.w;
    xa[12] = v3.x; xa[13] = v3.y; xa[14] = v3.z; xa[15] = v3.w;
  }
#pragma unroll
  for (int c = 1; c <= 14; ++c)
    acc[c - 1] = fmaf(w2, xa[c + 1], fmaf(w1, xa[c], fmaf(w0, xa[c - 1], acc[c - 1])));
  float xc[15];
  xc[0] = xa[14]; xc[1] = xa[15];
  {
    float4 v4 = rp[4 ^ sw];
    float4 v5 = rp[5 ^ sw];
    float4 v6 = rp[6 ^ sw];
    float4 v7 = rp[7 ^ sw];
    xc[2] = v4.x; xc[3] = v4.y; xc[4] = v4.z; xc[5] = v4.w;
    xc[6] = v5.x; xc[7] = v5.y; xc[8] = v5.z; xc[9] = v5.w;
    xc[10] = v6.x; xc[11] = v6.y; xc[12] = v6.z; xc[13] = v6.w;
    xc[14] = v7.x;
  }
#pragma unroll
  for (int k = 0; k < 13; ++k)
    acc[14 + k] = fmaf(w2, xc[k + 2], fmaf(w1, xc[k + 1], fmaf(w0, xc[k], acc[14 + k])));
}

// One (layer, t) step for batch b. lx: [IC+136][32] swizzled (x rows,
// h rows, 8 cond rows). lrh: [128][32] swizzled. lu: [128][27] plain.
template <int IC, bool XN>
__device__ void step_body(const Params& p, int b, int t, bool hv,
    const float* __restrict__ xpre, const float* __restrict__ xs,
    const float* __restrict__ xg, const float* __restrict__ xb,
    const float* __restrict__ hpre, const float* __restrict__ hs,
    const float* __restrict__ hg, const float* __restrict__ hb,
    const float4* __restrict__ wtg, const float* __restrict__ gbias,
    const float4* __restrict__ wtc, const float* __restrict__ cbias,
    const float4* __restrict__ wta, const float* __restrict__ abias,
    float* __restrict__ pre_out, float* __restrict__ sums_out,
    float* lx, float* lrh, float* lu) {
  const int tid = threadIdx.x;
  constexpr int ROWS = IC + 136;
  // ---- stage (normalized x, normalized h, cond rows): 4 threads/row ----
  {
    const int q = tid & 3;
    const int w0c = q * 7;
    const int wcnt = (q == 3) ? 6 : 7;
    for (int r = tid >> 2; r < ROWS; r += 256) {
      float sc = 1.f, sh = 0.f;
      const float* src = nullptr;
      if (r < IC) {
        if (XN) {
          bn_coef(xs, xg, xb, r, sc, sh);
          src = xpre + ((size_t)b * Hn + r) * Wn;
        } else {
          src = p.in + (((size_t)b * Tn + t) * Cn + r) * Wn;
        }
      } else if (r < IC + 128) {
        if (hv) {
          bn_coef(hs, hg, hb, r - IC, sc, sh);
          src = hpre + ((size_t)b * Hn + (r - IC)) * Wn;
        }
      } else {
        src = p.in + (((size_t)b * Tn + t) * Cn + 56 + (r - IC - 128)) * Wn;
      }
      if (q == 0) lx[swz(r, 0)] = 0.f;
      if (q == 3) {
        lx[swz(r, 28)] = 0.f; lx[swz(r, 29)] = 0.f;
        lx[swz(r, 30)] = 0.f; lx[swz(r, 31)] = 0.f;
      }
      if (src) {
        for (int j = 0; j < wcnt; ++j) {
          float v = __builtin_nontemporal_load(src + w0c + j);
          lx[swz(r, 1 + w0c + j)] = v * sc + sh;
        }
      } else {
        for (int j = 0; j < wcnt; ++j) lx[swz(r, 1 + w0c + j)] = 0.f;
      }
    }
  }
  __syncthreads();
  // ---- gates: thread = (och 0..255, rowchunk rc 0..3), all 27 w ----
  {
    const int rc = tid & 3;
    const int och = tid >> 2;
    float acc[27];
#pragma unroll
    for (int j = 0; j < 27; ++j) acc[j] = 0.f;
    const int rows = hv ? IC + 128 : IC;
    for (int i = rc; i < rows; i += 4) {
      float4 w = wtg[i * 256 + och];
      conv_row(lx + i * 32, i & 7, w.x, w.y, w.z, acc);
    }
#pragma unroll
    for (int j = 0; j < 27; ++j) {
      acc[j] += __shfl_xor(acc[j], 1);
      acc[j] += __shfl_xor(acc[j], 2);
    }
    if (rc == 0) {
      const float bias = gbias[och];
      if (och < 128) {
        lrh[swz(och, 0)] = 0.f;
        lrh[swz(och, 28)] = 0.f; lrh[swz(och, 29)] = 0.f;
        lrh[swz(och, 30)] = 0.f; lrh[swz(och, 31)] = 0.f;
#pragma unroll
        for (int c = 1; c <= 27; ++c) {
          float gv = sigm(acc[c - 1] + bias);
          lrh[swz(och, c)] = gv * lx[swz(IC + och, c)];
        }
      } else {
        const int ch = och - 128;
#pragma unroll
        for (int c = 1; c <= 27; ++c)
          lu[ch * 27 + (c - 1)] = sigm(acc[c - 1] + bias);
      }
    }
  }
  __syncthreads();
  // ---- cnm: thread = (ch 0..127, rowchunk rc8 0..7), all 27 w ----
  {
    const int rc8 = tid & 7;
    const int ch = tid >> 3;
    float acc[27];
#pragma unroll
    for (int j = 0; j < 27; ++j) acc[j] = 0.f;
    for (int i = rc8; i < IC; i += 8) {  // x part
      float4 w = wtc[i * 128 + ch];
      conv_row(lx + i * 32, i & 7, w.x, w.y, w.z, acc);
    }
    if (hv) {
      for (int i = rc8; i < 128; i += 8) {  // reset*h part
        float4 w = wtc[(IC + i) * 128 + ch];
        conv_row(lrh + i * 32, i & 7, w.x, w.y, w.z, acc);
      }
    }
    {  // cond part: exactly one row per rowchunk
      const int i = rc8;
      float4 w = wta[i * 128 + ch];
      const int r = IC + 128 + i;
      conv_row(lx + r * 32, r & 7, w.x, w.y, w.z, acc);
    }
#pragma unroll
    for (int j = 0; j < 27; ++j) {
      acc[j] += __shfl_xor(acc[j], 1);
      acc[j] += __shfl_xor(acc[j], 2);
      acc[j] += __shfl_xor(acc[j], 4);
    }
    if (rc8 == 0) {
      const float cb = cbias[ch] + abias[ch];
      float s1 = 0.f, s2 = 0.f;
#pragma unroll
      for (int c = 1; c <= 27; ++c) {
        float u = lu[ch * 27 + (c - 1)];
        float hn = lx[swz(IC + ch, c)];  // normalized h (0 if !hv)
        float z = (1.f - u) * hn + u * (acc[c - 1] + cb);
        float pv;
        if (z > 20.f) {
          pv = z;
        } else {
          float q = 1.f + __expf(z);
          float q2 = q * q;
          pv = z * (q2 - 1.f) / (q2 + 1.f);  // z*tanh(softplus(z))
        }
        __builtin_nontemporal_store(pv,
            pre_out + ((size_t)b * Hn + ch) * Wn + (c - 1));
        s1 += pv;
        s2 += pv * pv;
      }
      atomicAdd(&sums_out[2 * ch], s1);
      atomicAdd(&sums_out[2 * ch + 1], s2);
    }
  }
}

// device-wide barrier: monotone counter, one atomic per block
__device__ __forceinline__ void gbar(unsigned* cnt, unsigned target) {
  __syncthreads();
  if (threadIdx.x == 0) {
    __threadfence();
    atomicAdd(cnt, 1u);
    while (__hip_atomic_load(cnt, __ATOMIC_RELAXED, __HIP_MEMORY_SCOPE_AGENT) < target) {
      __builtin_amdgcn_s_sleep(8);
    }
    __threadfence();
  }
  __syncthreads();
}

__global__ __launch_bounds__(1024, 2) void k_all(Params p) {
  __shared__ __align__(16) float lx[264 * 32];   // 33792 B
  __shared__ __align__(16) float lrh[128 * 32];  // 16384 B
  __shared__ float lu[128 * 27];                 // 13824 B
  const int bid = blockIdx.x;
  const bool L1b = bid >= 128;
  const int b = L1b ? bid - 128 : bid;
  float* pre1[2] = {p.pre1a, p.pre1b};
  float* pre2[2] = {p.pre2a, p.pre2b};
  for (int ph = 0; ph < 65; ++ph) {
    if (!L1b) {
      if (ph < 64) {
        const int t = ph;
        const bool hv = t > 0;
        step_body<Cn, false>(p, b, t, hv,
            nullptr, nullptr, nullptr, nullptr,
            hv ? pre1[(t - 1) & 1] : nullptr,
            hv ? p.sums + (size_t)(t - 1) * 256 : nullptr, p.bg0, p.bb0,
            p.wt_g0, p.gb0, p.wt_c0, p.cb0, p.wt_a0, p.ab0,
            pre1[t & 1], p.sums + (size_t)t * 256, lx, lrh, lu);
      }
    } else {
      if (ph >= 1) {
        const int t = ph - 1;
        const bool hv = t > 0;
        step_body<Hn, true>(p, b, t, hv,
            pre1[t & 1], p.sums + (size_t)t * 256, p.bg0, p.bb0,
            hv ? pre2[(t - 1) & 1] : nullptr,
            hv ? p.sums + (size_t)(64 + t - 1) * 256 : nullptr, p.bg1, p.bb1,
            p.wt_g1, p.gb1, p.wt_c1, p.cb1, p.wt_a1, p.ab1,
            pre2[t & 1], p.sums + (size_t)(64 + t) * 256, lx, lrh, lu);
      }
    }
    gbar(p.cnt, (unsigned)(ph + 1) * 256u);
  }
  // ---- output: blocks 0..127, one batch each ----
  if (!L1b) {
    const float* p63 = pre2[1];
    const float* p62 = pre2[0];
    const float* s63 = p.sums + (size_t)(64 + 63) * 256;
    const float* s62 = p.sums + (size_t)(64 + 62) * 256;
    const int tid = threadIdx.x;
    float acc = 0.f;
    for (int idx = tid; idx < Hn * Wn; idx += 1024) {
      int o = idx / Wn;
      float sc3, sh3, sc2, sh2;
      bn_coef(s63, p.bg1, p.bb1, o, sc3, sh3);
      bn_coef(s62, p.bg1, p.bb1, o, sc2, sh2);
      float v3 = p63[(size_t)b * Hn * Wn + idx] * sc3 + sh3;
      float v2 = p62[(size_t)b * Hn * Wn + idx] * sc2 + sh2;
      acc += (v3 - v2) * p.concw[idx];
    }
    lx[tid] = acc;
    __syncthreads();
    for (int s = 512; s > 0; s >>= 1) {
      if (tid < s) lx[tid] += lx[tid + s];
      __syncthreads();
    }
    if (tid == 0) p.out[b] = 0.99f * lx[0];
  }
}

// repack (M, IC, 3) -> float4 [i][o] = (w0, w1, w2, 0)
__global__ void k_twt4(const float* __restrict__ src, float4* __restrict__ dst,
                       int M, int IC) {
  int idx = blockIdx.x * 256 + threadIdx.x;
  int total = M * IC;
  if (idx >= total) return;
  int i = idx / M;
  int o = idx - i * M;
  const float* s = src + ((size_t)o * IC + i) * 3;
  dst[idx] = make_float4(s[0], s[1], s[2], 0.f);
}

extern "C" void kernel_launch(void* const* d_in, const int* in_sizes, int n_in,
                              void* d_out, int out_size, void* d_ws,
                              size_t ws_size, hipStream_t stream) {
  const float* in = (const float*)d_in[0];
  const float* gw0 = (const float*)d_in[1];
  const float* gb0 = (const float*)d_in[2];
  const float* cw0 = (const float*)d_in[3];
  const float* cb0 = (const float*)d_in[4];
  const float* aw0 = (const float*)d_in[5];
  const float* ab0 = (const float*)d_in[6];
  const float* bg0 = (const float*)d_in[7];
  const float* bb0 = (const float*)d_in[8];
  const float* gw1 = (const float*)d_in[9];
  const float* gb1 = (const float*)d_in[10];
  const float* cw1 = (const float*)d_in[11];
  const float* cb1 = (const float*)d_in[12];
  const float* aw1 = (const float*)d_in[13];
  const float* ab1 = (const float*)d_in[14];
  const float* bg1 = (const float*)d_in[15];
  const float* bb1 = (const float*)d_in[16];
  const float* concw = (const float*)d_in[17];
  float* out = (float*)d_out;

  float* ws = (float*)d_ws;
  size_t off = 0;
  float4* wt_g0 = (float4*)(ws + off); off += 4 * 192 * 256;
  float4* wt_c0 = (float4*)(ws + off); off += 4 * 192 * 128;
  float4* wt_a0 = (float4*)(ws + off); off += 4 * 8 * 128;
  float4* wt_g1 = (float4*)(ws + off); off += 4 * 256 * 256;
  float4* wt_c1 = (float4*)(ws + off); off += 4 * 256 * 128;
  float4* wt_a1 = (float4*)(ws + off); off += 4 * 8 * 128;
  const size_t PRE = (size_t)Bn * Hn * Wn;  // 442368
  float* pre1a = ws + off; off += PRE;
  float* pre1b = ws + off; off += PRE;
  float* pre2a = ws + off; off += PRE;
  float* pre2b = ws + off; off += PRE;
  float* sums = ws + off; off += 2 * 64 * 256;
  unsigned* cnt = (unsigned*)(ws + off); off += 16;
  if (ws_size < off * sizeof(float)) return;

  // zero sums + barrier counter (contiguous)
  hipMemsetAsync(sums, 0, (2 * 64 * 256 + 16) * sizeof(float), stream);

  auto tw = [&](const float* s, float4* d, int M, int IC) {
    int tot = M * IC;
    k_twt4<<<(tot + 255) / 256, 256, 0, stream>>>(s, d, M, IC);
  };
  tw(gw0, wt_g0, 256, 192);
  tw(cw0, wt_c0, 128, 192);
  tw(aw0, wt_a0, 128, 8);
  tw(gw1, wt_g1, 256, 256);
  tw(cw1, wt_c1, 128, 256);
  tw(aw1, wt_a1, 128, 8);

  Params prm;
  prm.in = in;
  prm.wt_g0 = wt_g0; prm.gb0 = gb0;
  prm.wt_c0 = wt_c0; prm.cb0 = cb0;
  prm.wt_a0 = wt_a0; prm.ab0 = ab0;
  prm.bg0 = bg0; prm.bb0 = bb0;
  prm.wt_g1 = wt_g1; prm.gb1 = gb1;
  prm.wt_c1 = wt_c1; prm.cb1 = cb1;
  prm.wt_a1 = wt_a1; prm.ab1 = ab1;
  prm.bg1 = bg1; prm.bb1 = bb1;
  prm.concw = concw;
  prm.pre1a = pre1a; prm.pre1b = pre1b;
  prm.pre2a = pre2a; prm.pre2b = pre2b;
  prm.sums = sums; prm.cnt = cnt; prm.out = out;

  k_all<<<256, 1024, 0, stream>>>(prm);
}

// Round 5
// 7184.256 us; speedup vs baseline: 1.1683x; 1.1683x over previous
//
#include <hip/hip_runtime.h>
#include <math.h>

#define Bn 128
#define Tn 64
#define Cn 64
#define Wn 27
#define Hn 128
#define EPSf 1e-5f
#define NBWf 3456.0f

struct Params {
  const float* in;
  const float4* wt_g0; const float* gb0;
  const float4* wt_c0; const float* cb0;
  const float4* wt_a0; const float* ab0;
  const float* bg0; const float* bb0;
  const float4* wt_g1; const float* gb1;
  const float4* wt_c1; const float* cb1;
  const float4* wt_a1; const float* ab1;
  const float* bg1; const float* bb1;
  const float* concw;
  float* pre1a; float* pre1b; float* pre2a; float* pre2b;
  float* sums;        // [2*64][256] : per (layer,t) 128 ch x (sum, sumsq)
  unsigned* cnt;      // global barrier counter
  float* out;
};

__device__ __forceinline__ void bn_coef(const float* __restrict__ sums,
                                        const float* __restrict__ g,
                                        const float* __restrict__ b,
                                        int c, float& sc, float& sh) {
  float s1 = sums[2 * c], s2 = sums[2 * c + 1];
  float mean = s1 * (1.0f / NBWf);
  float var = s2 * (1.0f / NBWf) - mean * mean;
  sc = g[c] * rsqrtf(var + EPSf);
  sh = b[c] - mean * sc;
}

__device__ __forceinline__ float sigm(float x) {
  return 1.0f / (1.0f + __expf(-x));
}

// swizzled scalar index: row stride 32 floats; 16B blocks XORed by (row&7)
__device__ __forceinline__ int swz(int row, int c) {
  return row * 32 + ((((c >> 2) ^ (row & 7)) & 7) << 2) + (c & 3);
}

// one conv row: acc[27] += w0*x[c-1] + w1*x[c] + w2*x[c+1], cols 0..28
// (col 0 and 28 are zero pads), x read as swizzled float4 blocks.
__device__ __forceinline__ void conv_row(const float* __restrict__ rowbase,
                                         int sw, float w0, float w1, float w2,
                                         float* __restrict__ acc) {
  const float4* rp = (const float4*)rowbase;
  float xa[16];
  {
    float4 v0 = rp[0 ^ sw];
    float4 v1 = rp[1 ^ sw];
    float4 v2 = rp[2 ^ sw];
    float4 v3 = rp[3 ^ sw];
    xa[0] = v0.x; xa[1] = v0.y; xa[2] = v0.z; xa[3] = v0.w;
    xa[4] = v1.x; xa[5] = v1.y; xa[6] = v1.z; xa[7] = v1.w;
    xa[8] = v2.x; xa[9] = v2.y; xa[10] = v2.z; xa[11] = v2.w;
    xa[12] = v3.x; xa[13] = v3.y; xa[14] = v3.z; xa[15] = v3.w;
  }
#pragma unroll
  for (int c = 1; c <= 14; ++c)
    acc[c - 1] = fmaf(w2, xa[c + 1], fmaf(w1, xa[c], fmaf(w0, xa[c - 1], acc[c - 1])));
  float xc[15];
  xc[0] = xa[14]; xc[1] = xa[15];
  {
    float4 v4 = rp[4 ^ sw];
    float4 v5 = rp[5 ^ sw];
    float4 v6 = rp[6 ^ sw];
    float4 v7 = rp[7 ^ sw];
    xc[2] = v4.x; xc[3] = v4.y; xc[4] = v4.z; xc[5] = v4.w;
    xc[6] = v5.x; xc[7] = v5.y; xc[8] = v5.z; xc[9] = v5.w;
    xc[10] = v6.x; xc[11] = v6.y; xc[12] = v6.z; xc[13] = v6.w;
    xc[14] = v7.x;
  }
#pragma unroll
  for (int k = 0; k < 13; ++k)
    acc[14 + k] = fmaf(w2, xc[k + 2], fmaf(w1, xc[k + 1], fmaf(w0, xc[k], acc[14 + k])));
}

// One (layer, t) step for batch b. lx: [IC+136][32] swizzled (x rows,
// h rows, 8 cond rows). lrh: [128][32] swizzled. lu: [128][27] plain.
template <int IC, bool XN>
__device__ void step_body(const Params& p, int b, int t, bool hv,
    const float* __restrict__ xpre, const float* __restrict__ xs,
    const float* __restrict__ xg, const float* __restrict__ xb,
    const float* __restrict__ hpre, const float* __restrict__ hs,
    const float* __restrict__ hg, const float* __restrict__ hb,
    const float4* __restrict__ wtg, const float* __restrict__ gbias,
    const float4* __restrict__ wtc, const float* __restrict__ cbias,
    const float4* __restrict__ wta, const float* __restrict__ abias,
    float* __restrict__ pre_out, float* __restrict__ sums_out,
    float* lx, float* lrh, float* lu) {
  const int tid = threadIdx.x;
  constexpr int ROWS = IC + 136;
  // ---- stage (normalized x, normalized h, cond rows): 4 threads/row ----
  {
    const int q = tid & 3;
    const int w0c = q * 7;
    const int wcnt = (q == 3) ? 6 : 7;
    for (int r = tid >> 2; r < ROWS; r += 256) {
      float sc = 1.f, sh = 0.f;
      const float* src = nullptr;
      if (r < IC) {
        if (XN) {
          bn_coef(xs, xg, xb, r, sc, sh);
          src = xpre + ((size_t)b * Hn + r) * Wn;
        } else {
          src = p.in + (((size_t)b * Tn + t) * Cn + r) * Wn;
        }
      } else if (r < IC + 128) {
        if (hv) {
          bn_coef(hs, hg, hb, r - IC, sc, sh);
          src = hpre + ((size_t)b * Hn + (r - IC)) * Wn;
        }
      } else {
        src = p.in + (((size_t)b * Tn + t) * Cn + 56 + (r - IC - 128)) * Wn;
      }
      if (q == 0) lx[swz(r, 0)] = 0.f;
      if (q == 3) {
        lx[swz(r, 28)] = 0.f; lx[swz(r, 29)] = 0.f;
        lx[swz(r, 30)] = 0.f; lx[swz(r, 31)] = 0.f;
      }
      if (src) {
        for (int j = 0; j < wcnt; ++j)
          lx[swz(r, 1 + w0c + j)] = src[w0c + j] * sc + sh;
      } else {
        for (int j = 0; j < wcnt; ++j) lx[swz(r, 1 + w0c + j)] = 0.f;
      }
    }
  }
  __syncthreads();
  // ---- gates: thread = (och 0..255, rowchunk rc 0..3), all 27 w ----
  {
    const int rc = tid & 3;
    const int och = tid >> 2;
    float acc[27];
#pragma unroll
    for (int j = 0; j < 27; ++j) acc[j] = 0.f;
    const int rows = hv ? IC + 128 : IC;
    for (int i = rc; i < rows; i += 4) {
      float4 w = wtg[i * 256 + och];
      conv_row(lx + i * 32, i & 7, w.x, w.y, w.z, acc);
    }
#pragma unroll
    for (int j = 0; j < 27; ++j) {
      acc[j] += __shfl_xor(acc[j], 1);
      acc[j] += __shfl_xor(acc[j], 2);
    }
    // epilogue distributed across rc lanes: lane rc handles j = rc, rc+4, ...
    const float bias = gbias[och];
    if (och < 128) {
      if (rc == 0) {
        lrh[swz(och, 0)] = 0.f;
        lrh[swz(och, 28)] = 0.f; lrh[swz(och, 29)] = 0.f;
        lrh[swz(och, 30)] = 0.f; lrh[swz(och, 31)] = 0.f;
      }
#pragma unroll
      for (int j = rc; j < 27; j += 4) {
        float gv = sigm(acc[j] + bias);
        lrh[swz(och, j + 1)] = gv * lx[swz(IC + och, j + 1)];
      }
    } else {
      const int ch = och - 128;
#pragma unroll
      for (int j = rc; j < 27; j += 4)
        lu[ch * 27 + j] = sigm(acc[j] + bias);
    }
  }
  __syncthreads();
  // ---- cnm: thread = (ch 0..127, rowchunk rc8 0..7), all 27 w ----
  {
    const int rc8 = tid & 7;
    const int ch = tid >> 3;
    float acc[27];
#pragma unroll
    for (int j = 0; j < 27; ++j) acc[j] = 0.f;
    for (int i = rc8; i < IC; i += 8) {  // x part
      float4 w = wtc[i * 128 + ch];
      conv_row(lx + i * 32, i & 7, w.x, w.y, w.z, acc);
    }
    if (hv) {
      for (int i = rc8; i < 128; i += 8) {  // reset*h part
        float4 w = wtc[(IC + i) * 128 + ch];
        conv_row(lrh + i * 32, i & 7, w.x, w.y, w.z, acc);
      }
    }
    {  // cond part: exactly one row per rowchunk
      const int i = rc8;
      float4 w = wta[i * 128 + ch];
      const int r = IC + 128 + i;
      conv_row(lx + r * 32, r & 7, w.x, w.y, w.z, acc);
    }
#pragma unroll
    for (int j = 0; j < 27; ++j) {
      acc[j] += __shfl_xor(acc[j], 1);
      acc[j] += __shfl_xor(acc[j], 2);
      acc[j] += __shfl_xor(acc[j], 4);
    }
    // epilogue distributed: lane rc8 handles j = rc8, rc8+8, ...
    const float cb = cbias[ch] + abias[ch];
    float s1 = 0.f, s2 = 0.f;
#pragma unroll
    for (int j = rc8; j < 27; j += 8) {
      float u = lu[ch * 27 + j];
      float hn = lx[swz(IC + ch, j + 1)];  // normalized h (0 if !hv)
      float z = (1.f - u) * hn + u * (acc[j] + cb);
      float pv;
      if (z > 20.f) {
        pv = z;
      } else {
        float q = 1.f + __expf(z);
        float q2 = q * q;
        pv = z * (q2 - 1.f) / (q2 + 1.f);  // z*tanh(softplus(z))
      }
      pre_out[((size_t)b * Hn + ch) * Wn + j] = pv;
      s1 += pv;
      s2 += pv * pv;
    }
    s1 += __shfl_xor(s1, 1); s2 += __shfl_xor(s2, 1);
    s1 += __shfl_xor(s1, 2); s2 += __shfl_xor(s2, 2);
    s1 += __shfl_xor(s1, 4); s2 += __shfl_xor(s2, 4);
    if (rc8 == 0) {
      atomicAdd(&sums_out[2 * ch], s1);
      atomicAdd(&sums_out[2 * ch + 1], s2);
    }
  }
}

// device-wide barrier: monotone counter, one atomic per block
__device__ __forceinline__ void gbar(unsigned* cnt, unsigned target) {
  __syncthreads();
  if (threadIdx.x == 0) {
    __threadfence();
    atomicAdd(cnt, 1u);
    while (__hip_atomic_load(cnt, __ATOMIC_RELAXED, __HIP_MEMORY_SCOPE_AGENT) < target) {
      __builtin_amdgcn_s_sleep(8);
    }
    __threadfence();
  }
  __syncthreads();
}

__global__ __launch_bounds__(1024, 2) void k_all(Params p) {
  __shared__ __align__(16) float lx[264 * 32];   // 33792 B
  __shared__ __align__(16) float lrh[128 * 32];  // 16384 B
  __shared__ float lu[128 * 27];                 // 13824 B
  const int bid = blockIdx.x;
  // XCD-aware partition: XCD = bid % 8 (round-robin dispatch). Layer 0 on
  // XCDs 0-3, layer 1 on XCDs 4-7 -> each XCD's L2 holds ONE layer's weights.
  const bool L1b = (bid & 7) >= 4;
  const int b = (bid >> 3) * 4 + (bid & 3);
  float* pre1[2] = {p.pre1a, p.pre1b};
  float* pre2[2] = {p.pre2a, p.pre2b};
  for (int ph = 0; ph < 65; ++ph) {
    if (!L1b) {
      if (ph < 64) {
        const int t = ph;
        const bool hv = t > 0;
        step_body<Cn, false>(p, b, t, hv,
            nullptr, nullptr, nullptr, nullptr,
            hv ? pre1[(t - 1) & 1] : nullptr,
            hv ? p.sums + (size_t)(t - 1) * 256 : nullptr, p.bg0, p.bb0,
            p.wt_g0, p.gb0, p.wt_c0, p.cb0, p.wt_a0, p.ab0,
            pre1[t & 1], p.sums + (size_t)t * 256, lx, lrh, lu);
      }
    } else {
      if (ph >= 1) {
        const int t = ph - 1;
        const bool hv = t > 0;
        step_body<Hn, true>(p, b, t, hv,
            pre1[t & 1], p.sums + (size_t)t * 256, p.bg0, p.bb0,
            hv ? pre2[(t - 1) & 1] : nullptr,
            hv ? p.sums + (size_t)(64 + t - 1) * 256 : nullptr, p.bg1, p.bb1,
            p.wt_g1, p.gb1, p.wt_c1, p.cb1, p.wt_a1, p.ab1,
            pre2[t & 1], p.sums + (size_t)(64 + t) * 256, lx, lrh, lu);
      }
    }
    gbar(p.cnt, (unsigned)(ph + 1) * 256u);
  }
  // ---- output: layer-0 blocks, one batch each ----
  if (!L1b) {
    const float* p63 = pre2[1];
    const float* p62 = pre2[0];
    const float* s63 = p.sums + (size_t)(64 + 63) * 256;
    const float* s62 = p.sums + (size_t)(64 + 62) * 256;
    const int tid = threadIdx.x;
    float acc = 0.f;
    for (int idx = tid; idx < Hn * Wn; idx += 1024) {
      int o = idx / Wn;
      float sc3, sh3, sc2, sh2;
      bn_coef(s63, p.bg1, p.bb1, o, sc3, sh3);
      bn_coef(s62, p.bg1, p.bb1, o, sc2, sh2);
      float v3 = p63[(size_t)b * Hn * Wn + idx] * sc3 + sh3;
      float v2 = p62[(size_t)b * Hn * Wn + idx] * sc2 + sh2;
      acc += (v3 - v2) * p.concw[idx];
    }
    lx[tid] = acc;
    __syncthreads();
    for (int s = 512; s > 0; s >>= 1) {
      if (tid < s) lx[tid] += lx[tid + s];
      __syncthreads();
    }
    if (tid == 0) p.out[b] = 0.99f * lx[0];
  }
}

// repack (M, IC, 3) -> float4 [i][o] = (w0, w1, w2, 0)
__global__ void k_twt4(const float* __restrict__ src, float4* __restrict__ dst,
                       int M, int IC) {
  int idx = blockIdx.x * 256 + threadIdx.x;
  int total = M * IC;
  if (idx >= total) return;
  int i = idx / M;
  int o = idx - i * M;
  const float* s = src + ((size_t)o * IC + i) * 3;
  dst[idx] = make_float4(s[0], s[1], s[2], 0.f);
}

extern "C" void kernel_launch(void* const* d_in, const int* in_sizes, int n_in,
                              void* d_out, int out_size, void* d_ws,
                              size_t ws_size, hipStream_t stream) {
  const float* in = (const float*)d_in[0];
  const float* gw0 = (const float*)d_in[1];
  const float* gb0 = (const float*)d_in[2];
  const float* cw0 = (const float*)d_in[3];
  const float* cb0 = (const float*)d_in[4];
  const float* aw0 = (const float*)d_in[5];
  const float* ab0 = (const float*)d_in[6];
  const float* bg0 = (const float*)d_in[7];
  const float* bb0 = (const float*)d_in[8];
  const float* gw1 = (const float*)d_in[9];
  const float* gb1 = (const float*)d_in[10];
  const float* cw1 = (const float*)d_in[11];
  const float* cb1 = (const float*)d_in[12];
  const float* aw1 = (const float*)d_in[13];
  const float* ab1 = (const float*)d_in[14];
  const float* bg1 = (const float*)d_in[15];
  const float* bb1 = (const float*)d_in[16];
  const float* concw = (const float*)d_in[17];
  float* out = (float*)d_out;

  float* ws = (float*)d_ws;
  size_t off = 0;
  float4* wt_g0 = (float4*)(ws + off); off += 4 * 192 * 256;
  float4* wt_c0 = (float4*)(ws + off); off += 4 * 192 * 128;
  float4* wt_a0 = (float4*)(ws + off); off += 4 * 8 * 128;
  float4* wt_g1 = (float4*)(ws + off); off += 4 * 256 * 256;
  float4* wt_c1 = (float4*)(ws + off); off += 4 * 256 * 128;
  float4* wt_a1 = (float4*)(ws + off); off += 4 * 8 * 128;
  const size_t PRE = (size_t)Bn * Hn * Wn;  // 442368
  float* pre1a = ws + off; off += PRE;
  float* pre1b = ws + off; off += PRE;
  float* pre2a = ws + off; off += PRE;
  float* pre2b = ws + off; off += PRE;
  float* sums = ws + off; off += 2 * 64 * 256;
  unsigned* cnt = (unsigned*)(ws + off); off += 16;
  if (ws_size < off * sizeof(float)) return;

  // zero sums + barrier counter (contiguous)
  hipMemsetAsync(sums, 0, (2 * 64 * 256 + 16) * sizeof(float), stream);

  auto tw = [&](const float* s, float4* d, int M, int IC) {
    int tot = M * IC;
    k_twt4<<<(tot + 255) / 256, 256, 0, stream>>>(s, d, M, IC);
  };
  tw(gw0, wt_g0, 256, 192);
  tw(cw0, wt_c0, 128, 192);
  tw(aw0, wt_a0, 128, 8);
  tw(gw1, wt_g1, 256, 256);
  tw(cw1, wt_c1, 128, 256);
  tw(aw1, wt_a1, 128, 8);

  Params prm;
  prm.in = in;
  prm.wt_g0 = wt_g0; prm.gb0 = gb0;
  prm.wt_c0 = wt_c0; prm.cb0 = cb0;
  prm.wt_a0 = wt_a0; prm.ab0 = ab0;
  prm.bg0 = bg0; prm.bb0 = bb0;
  prm.wt_g1 = wt_g1; prm.gb1 = gb1;
  prm.wt_c1 = wt_c1; prm.cb1 = cb1;
  prm.wt_a1 = wt_a1; prm.ab1 = ab1;
  prm.bg1 = bg1; prm.bb1 = bb1;
  prm.concw = concw;
  prm.pre1a = pre1a; prm.pre1b = pre1b;
  prm.pre2a = pre2a; prm.pre2b = pre2b;
  prm.sums = sums; prm.cnt = cnt; prm.out = out;

  k_all<<<256, 1024, 0, stream>>>(prm);
}